// Round 5
// baseline (322.161 us; speedup 1.0000x reference)
//
#include <hip/hip_runtime.h>
#include <math.h>

#define N 4096
#define TOTAL (N * N)
#define MED_RANK 8388607u  // (TOTAL-1)/2

// monotonic float->uint key
__device__ __forceinline__ unsigned fkey(float f) {
    unsigned u = __float_as_uint(f);
    return (u & 0x80000000u) ? ~u : (u | 0x80000000u);
}

// ============================================================
// K1: Sobel (sequential fp32, row-major taps) -> fp32 products ->
// 49-tap gaussian as sequential fp32 mul/add in row-major (dy,dx)
// order -> fp32 R (left-assoc). Fused radix-hist pass 1.
// Block: 256 threads = 256 output cols; RT=64 output rows.
// Ring accumulators visit product rows dy=0..6 in ascending order,
// inner dx 0..6 ascending => exactly row-major sequential order.
// ============================================================
constexpr int RT = 64;

__global__ __launch_bounds__(256) void k1_kernel(
    const float* __restrict__ x, const float* __restrict__ gk,
    float* __restrict__ R, unsigned* __restrict__ hist1) {
    __shared__ float xs[3][264];    // x rows ring (cols bx-4 .. bx+259)
    __shared__ float ps[3][264];    // fp32 product row (cols bx-3 .. bx+258)
    __shared__ unsigned lh[2048];

    const int tid = threadIdx.x;
    const int bx = blockIdx.x * 256;
    const int by = blockIdx.y * RT;

    for (int i = tid; i < 2048; i += 256) lh[i] = 0;

    // full 49 gaussian weights (wave-uniform -> scalar regs)
    float w49[49];
    #pragma unroll
    for (int k = 0; k < 49; k++) w49[k] = gk[k];

    // ring accumulators: slot k holds partials for out row r = ri+3-k
    float a0[7], a1[7], a2[7];
    #pragma unroll
    for (int k = 0; k < 7; k++) { a0[k] = 0.0f; a1[k] = 0.0f; a2[k] = 0.0f; }

    #pragma unroll
    for (int pre = 0; pre < 2; pre++) {
        int a = by - 4 + pre;
        for (int e = tid; e < 264; e += 256) {
            int col = bx - 4 + e;
            float v = 0.0f;
            if ((unsigned)a < N && (unsigned)col < N) v = x[(size_t)a * N + col];
            xs[pre][e] = v;
        }
    }

    for (int it = 0; it < RT + 6; ++it) {
        const int ri = by - 3 + it;  // product row this iter
        {
            int a = ri + 1;
            int slot = (it + 2) % 3;
            for (int e = tid; e < 264; e += 256) {
                int col = bx - 4 + e;
                float v = 0.0f;
                if ((unsigned)a < N && (unsigned)col < N) v = x[(size_t)a * N + col];
                xs[slot][e] = v;
            }
        }
        __syncthreads();

        {
            const int s0 = it % 3, s1 = (it + 1) % 3, s2 = (it + 2) % 3;
            for (int j = tid; j < 262; j += 256) {
                int pc = bx - 3 + j;
                float pxx = 0.0f, pyy = 0.0f, pxy = 0.0f;
                if ((unsigned)ri < N && (unsigned)pc < N) {
                    float A = xs[s0][j], B = xs[s0][j + 1], C = xs[s0][j + 2];
                    float D = xs[s1][j],                    F = xs[s1][j + 2];
                    float G = xs[s2][j], H = xs[s2][j + 1], I = xs[s2][j + 2];
                    // Ix: sequential fp32, row-major over [[-1,0,1],[-2,0,2],[-1,0,1]]
                    float ix = __fmul_rn(-1.0f, A);
                    ix = __fadd_rn(ix, C);
                    ix = __fadd_rn(ix, __fmul_rn(-2.0f, D));
                    ix = __fadd_rn(ix, __fmul_rn(2.0f, F));
                    ix = __fadd_rn(ix, __fmul_rn(-1.0f, G));
                    ix = __fadd_rn(ix, I);
                    // Iy: sequential fp32, row-major over [[-1,-2,-1],[0,0,0],[1,2,1]]
                    float iy = __fmul_rn(-1.0f, A);
                    iy = __fadd_rn(iy, __fmul_rn(-2.0f, B));
                    iy = __fadd_rn(iy, __fmul_rn(-1.0f, C));
                    iy = __fadd_rn(iy, G);
                    iy = __fadd_rn(iy, __fmul_rn(2.0f, H));
                    iy = __fadd_rn(iy, I);
                    pxx = __fmul_rn(ix, ix);
                    pyy = __fmul_rn(iy, iy);
                    pxy = __fmul_rn(ix, iy);
                }
                ps[0][j] = pxx; ps[1][j] = pyy; ps[2][j] = pxy;
            }
        }
        __syncthreads();

        // sequential fp32 accumulation: slot k <- weight row k (dy=k),
        // dx ascending, separate mul/add (no FMA).
        float p0[7], p1[7], p2[7];
        #pragma unroll
        for (int dx = 0; dx < 7; dx++) {
            p0[dx] = ps[0][tid + dx];
            p1[dx] = ps[1][tid + dx];
            p2[dx] = ps[2][tid + dx];
        }
        #pragma unroll
        for (int k = 0; k < 7; k++) {
            float t0 = a0[k], t1 = a1[k], t2 = a2[k];
            #pragma unroll
            for (int dx = 0; dx < 7; dx++) {
                float w = w49[k * 7 + dx];
                t0 = __fadd_rn(t0, __fmul_rn(w, p0[dx]));
                t1 = __fadd_rn(t1, __fmul_rn(w, p1[dx]));
                t2 = __fadd_rn(t2, __fmul_rn(w, p2[dx]));
            }
            a0[k] = t0; a1[k] = t1; a2[k] = t2;
        }

        int r = ri - 3;
        if (r >= by) {
            float sx2 = a0[6], sy2 = a1[6], sxy = a2[6];
            float tr = __fadd_rn(sx2, sy2);
            float e = __fsub_rn(__fmul_rn(sx2, sy2), __fmul_rn(sxy, sxy));
            float t3 = __fmul_rn(__fmul_rn(0.05f, tr), tr);
            float Rv = __fsub_rn(e, t3);
            R[(size_t)r * N + bx + tid] = Rv;
            atomicAdd(&lh[fkey(Rv) >> 21], 1u);
        }
        #pragma unroll
        for (int k = 6; k > 0; k--) { a0[k] = a0[k - 1]; a1[k] = a1[k - 1]; a2[k] = a2[k - 1]; }
        a0[0] = 0.0f; a1[0] = 0.0f; a2[0] = 0.0f;
    }

    __syncthreads();
    for (int i = tid; i < 2048; i += 256) {
        unsigned c = lh[i];
        if (c) atomicAdd(&hist1[i], c);
    }
}

// ============================================================
// Histogram passes 2,3 over fp32 keys.
// ============================================================
__global__ __launch_bounds__(256) void hist_kernel(
    const float4* __restrict__ R4, unsigned* __restrict__ hist,
    const unsigned* __restrict__ state,
    unsigned match_mask, int bin_shift, unsigned bin_mask, int nbins) {
    __shared__ unsigned lh[2048];
    for (int i = threadIdx.x; i < nbins; i += 256) lh[i] = 0;
    __syncthreads();

    const unsigned prefix = state[0] & match_mask;
    const int total4 = TOTAL / 4;
    const int stride = gridDim.x * 256;

    for (int i = blockIdx.x * 256 + threadIdx.x; i < total4; i += stride) {
        float4 v = R4[i];
        unsigned k0 = fkey(v.x), k1 = fkey(v.y), k2 = fkey(v.z), k3 = fkey(v.w);
        if ((k0 & match_mask) == prefix) atomicAdd(&lh[(k0 >> bin_shift) & bin_mask], 1u);
        if ((k1 & match_mask) == prefix) atomicAdd(&lh[(k1 >> bin_shift) & bin_mask], 1u);
        if ((k2 & match_mask) == prefix) atomicAdd(&lh[(k2 >> bin_shift) & bin_mask], 1u);
        if ((k3 & match_mask) == prefix) atomicAdd(&lh[(k3 >> bin_shift) & bin_mask], 1u);
    }
    __syncthreads();
    for (int i = threadIdx.x; i < nbins; i += 256) {
        unsigned c = lh[i];
        if (c) atomicAdd(&hist[i], c);
    }
}

// ============================================================
// Select: single block. state[0]=prefix, state[1]=rank,
// state[2]=median float bits (written on last pass).
// ============================================================
__global__ __launch_bounds__(256) void select_kernel(
    const unsigned* __restrict__ hist, unsigned* __restrict__ state,
    int nbins, int prefix_shift, int is_first, int is_last) {
    const int tid = threadIdx.x;
    const int bpt = nbins >> 8;

    const unsigned rank = is_first ? MED_RANK : state[1];
    const unsigned oldpref = is_first ? 0u : state[0];

    unsigned cnt[8];
    unsigned s = 0;
    for (int i = 0; i < bpt; i++) { cnt[i] = hist[tid * bpt + i]; s += cnt[i]; }
    __shared__ unsigned sc[256];
    sc[tid] = s;
    __syncthreads();
    for (int off = 1; off < 256; off <<= 1) {
        unsigned v = (tid >= off) ? sc[tid - off] : 0u;
        __syncthreads();
        sc[tid] += v;
        __syncthreads();
    }
    const unsigned incl = sc[tid];
    const unsigned excl = incl - s;

    if (rank >= excl && rank < incl) {
        unsigned r = rank - excl;
        for (int i = 0; i < bpt; i++) {
            if (r < cnt[i]) {
                unsigned bin = (unsigned)(tid * bpt + i);
                unsigned npref = oldpref | (bin << prefix_shift);
                state[0] = npref;
                state[1] = r;
                if (is_last) {
                    unsigned key = npref;
                    unsigned u = (key & 0x80000000u) ? (key ^ 0x80000000u) : ~key;
                    state[2] = u;
                }
                break;
            }
            r -= cnt[i];
        }
    }
}

// ============================================================
// K2: threshold by median + 7x7 separable max-pool + NMS (fp32)
// ============================================================
__global__ __launch_bounds__(256) void maxpool_kernel(
    const float* __restrict__ R, const unsigned* __restrict__ state,
    float* __restrict__ out) {
    __shared__ float rt[38 * 40];
    __shared__ float rm[38 * 32];

    const float med = __uint_as_float(state[2]);
    const int tid = threadIdx.x;
    const int bx = blockIdx.x * 32, by = blockIdx.y * 32;

    for (int i = tid; i < 38 * 38; i += 256) {
        int r = i / 38, c = i % 38;
        int gr = by - 3 + r, gc = bx - 3 + c;
        float v = -INFINITY;
        if ((unsigned)gr < N && (unsigned)gc < N) {
            v = R[(size_t)gr * N + gc];
            v = (v < med) ? 0.0f : v;
        }
        rt[r * 40 + c] = v;
    }
    __syncthreads();

    for (int i = tid; i < 38 * 32; i += 256) {
        int r = i / 32, c = i % 32;
        const float* p = &rt[r * 40 + c];
        float m = p[0];
        #pragma unroll
        for (int dx = 1; dx < 7; dx++) m = fmaxf(m, p[dx]);
        rm[i] = m;
    }
    __syncthreads();

    for (int i = tid; i < 32 * 32; i += 256) {
        int r = i / 32, c = i % 32;
        float m = rm[r * 32 + c];
        #pragma unroll
        for (int dy = 1; dy < 7; dy++) m = fmaxf(m, rm[(r + dy) * 32 + c]);
        float v = rt[(r + 3) * 40 + (c + 3)];
        out[(size_t)(by + r) * N + (bx + c)] = (v == m) ? v : 0.0f;
    }
}

// ============================================================
extern "C" void kernel_launch(void* const* d_in, const int* in_sizes, int n_in,
                              void* d_out, int out_size, void* d_ws, size_t ws_size,
                              hipStream_t stream) {
    const float* x = (const float*)d_in[0];
    const float* gk = (const float*)d_in[1];
    float* out = (float*)d_out;

    char* ws = (char*)d_ws;
    float* R = (float*)ws;                                 // 64 MB
    unsigned* hist1 = (unsigned*)(ws + (size_t)TOTAL * 4); // 2048 u32
    unsigned* hist2 = hist1 + 2048;                        // 2048 u32
    unsigned* hist3 = hist2 + 2048;                        // 1024 u32
    unsigned* state = hist3 + 1024;                        // 4 u32

    hipMemsetAsync(hist1, 0, (2048 + 2048 + 1024) * 4, stream);

    k1_kernel<<<dim3(N / 256, N / RT), 256, 0, stream>>>(x, gk, R, hist1);

    const float4* R4 = (const float4*)R;
    // pass 1: key bits 31..21 (hist fused into K1)
    select_kernel<<<1, 256, 0, stream>>>(hist1, state, 2048, 21, 1, 0);
    // pass 2: key bits 20..10
    hist_kernel<<<1024, 256, 0, stream>>>(R4, hist2, state, 0xFFE00000u, 10, 0x7FFu, 2048);
    select_kernel<<<1, 256, 0, stream>>>(hist2, state, 2048, 10, 0, 0);
    // pass 3: key bits 9..0
    hist_kernel<<<1024, 256, 0, stream>>>(R4, hist3, state, 0xFFFFFC00u, 0, 0x3FFu, 1024);
    select_kernel<<<1, 256, 0, stream>>>(hist3, state, 1024, 0, 0, 1);

    maxpool_kernel<<<dim3(N / 32, N / 32), 256, 0, stream>>>(R, state, out);
}